// Round 2
// baseline (632.660 us; speedup 1.0000x reference)
//
#include <hip/hip_runtime.h>

#define BT    2048
#define HDIM  1024
#define VDIM  32000
#define NSEQ  4
#define BETA  0.1f
#define IGNORE_IDX (-100)

typedef __attribute__((ext_vector_type(8))) short bf16x8;
typedef __attribute__((ext_vector_type(8))) unsigned short u16x8;
typedef __attribute__((ext_vector_type(4))) float f32x4;

// ---------------- ws layout ----------------
// floats: [0..4096)  ws_se ([2][BT])   [4096..8192) ws_tg ([2][BT])
// bytes 32768+: bf16 arrays: Xbf, Xrbf, Wbf, Wrbf (element offsets below)
#define WS_BF_BYTE  32768
#define XBF_OFF     0
#define XRBF_OFF    (BT * HDIM)                    // 2097152
#define WBF_OFF     (2 * BT * HDIM)                // 4194304
#define WRBF_OFF    (2 * BT * HDIM + VDIM * HDIM)  // 36962304
#define CVT_TOTAL   (2 * BT * HDIM + 2 * VDIM * HDIM)  // 69730304
#define WS_NEED     ((size_t)WS_BF_BYTE + (size_t)CVT_TOTAL * 2)

__device__ __forceinline__ unsigned short f2bf_rne(float f) {
  unsigned int u = __builtin_bit_cast(unsigned int, f);
  u += 0x7fffu + ((u >> 16) & 1u);
  return (unsigned short)(u >> 16);
}

__device__ __forceinline__ u16x8 cvt8(float4 a, float4 b) {
  u16x8 v;
  v[0] = f2bf_rne(a.x); v[1] = f2bf_rne(a.y); v[2] = f2bf_rne(a.z); v[3] = f2bf_rne(a.w);
  v[4] = f2bf_rne(b.x); v[5] = f2bf_rne(b.y); v[6] = f2bf_rne(b.z); v[7] = f2bf_rne(b.w);
  return v;
}

__global__ __launch_bounds__(256) void kto_zero_ws(float* p) {
  p[blockIdx.x * 256 + threadIdx.x] = 0.0f;
}

// fp32 -> bf16 one-shot conversion of X, Xr, W, Wr into ws. HBM-bound.
__global__ __launch_bounds__(256) void kto_convert(
    const float* __restrict__ X, const float* __restrict__ Xr,
    const float* __restrict__ W, const float* __restrict__ Wr,
    unsigned short* __restrict__ bf)
{
  size_t gid8 = ((size_t)blockIdx.x * 256 + threadIdx.x) * 8;
  if (gid8 >= (size_t)CVT_TOTAL) return;
  const float* src; size_t off;
  if (gid8 < (size_t)XRBF_OFF)      { src = X;  off = gid8; }
  else if (gid8 < (size_t)WBF_OFF)  { src = Xr; off = gid8 - XRBF_OFF; }
  else if (gid8 < (size_t)WRBF_OFF) { src = W;  off = gid8 - WBF_OFF; }
  else                              { src = Wr; off = gid8 - WRBF_OFF; }
  const float4* p = (const float4*)(src + off);
  float4 a = p[0], b = p[1];
  *(u16x8*)(bf + gid8) = cvt8(a, b);
}

#define GLD16(g, l) __builtin_amdgcn_global_load_lds( \
    (const __attribute__((address_space(1))) unsigned int*)(g), \
    (__attribute__((address_space(3))) unsigned int*)(l), 16, 0, 0)

// 256x256-tile deep-pipelined GEMM + logsumexp partials.
// grid = (BT/256, VDIM/256, 2 models) = (8, 125, 2), block = 512 (8 waves, 2Mx4N).
// LDS: 4 rotating 32KB slots, each one K-slice of 32 (A 256x64B + B 256x64B).
// Round-2 schedule: ONE phase / ONE barrier / ONE counted vmcnt per unit.
//   unit u: vmcnt(4) [unit u+1 landed, u+2 in flight]; barrier;
//           GLD unit u+3 -> slot (u+3)&3; read fB (slot u&3);
//           read fA[next] for unit u+1 (slot (u+1)&3)  <- overlaps MFMA below;
//           32 MFMA consuming fA[cur] (read during unit u-1) + fB.
// Slot audit: write (u+3)&3 distinct from u&3 (fB) and (u+1)&3 (nxtA);
// GLD issued AFTER the barrier so no wave can still have pending reads of
// the written slot (its reads were lgkm-drained before its previous MFMA).
__global__ __launch_bounds__(512, 2) void kto_lse_gemm_fast(
    const unsigned short* __restrict__ bf,
    const float* __restrict__ Bp, const float* __restrict__ Br,
    const int* __restrict__ target,
    float* __restrict__ ws_se, float* __restrict__ ws_tg)
{
  const int model = blockIdx.z;
  const unsigned short* __restrict__ Xb = bf + (model ? XRBF_OFF : XBF_OFF);
  const unsigned short* __restrict__ Wb = bf + (model ? WRBF_OFF : WBF_OFF);
  const float* __restrict__ Bv = model ? Br : Bp;

  // T1: bijective XCD swizzle. nwg=1000 per model, 8 XCDs, 125 blocks/XCD.
  const int lin  = blockIdx.x + (blockIdx.y << 3);
  const int wgid = (lin & 7) * 125 + (lin >> 3);
  const int mBase = (wgid & 7) * 256;
  const int nBase = (wgid >> 3) * 256;

  __shared__ unsigned short lds[4 * 16384];  // 128 KiB

  const int tid  = threadIdx.x;
  const int wave = tid >> 6;
  const int lane = tid & 63;
  const int q    = lane >> 4;
  const int c    = lane & 15;
  const int wm   = wave >> 2;   // 0..1  (M half)
  const int wn   = wave & 3;    // 0..3  (N quarter)

  // staging: unit = 32 segments of 1KB (16 rows x 64B); wave w owns segs 4w..4w+3.
  // LDS dest = wave-uniform base + lane*16 (linear). Source global chunk is
  // XOR-pre-swizzled so the read-side swizzle below finds its data (rule 21).
  const int lrow = lane >> 2;                       // row within 16-row segment
  const int lchk = (lane & 3) ^ ((lane >> 3) & 3);  // pre-swizzled 16B chunk

  const char* gsrc[4];
  int ldst[4];
  #pragma unroll
  for (int j = 0; j < 4; ++j) {
    const int seg = wave * 4 + j;
    if (seg < 16) {                                  // A: 16 segs = 256 rows
      const int row = mBase + seg * 16 + lrow;
      gsrc[j] = (const char*)Xb + (size_t)row * (HDIM * 2) + lchk * 16;
      ldst[j] = seg * 512;
    } else {                                         // B: 16 segs = 256 rows
      const int row = nBase + (seg - 16) * 16 + lrow;
      gsrc[j] = (const char*)Wb + (size_t)row * (HDIM * 2) + lchk * 16;
      ldst[j] = 8192 + (seg - 16) * 512;
    }
  }

  // frag-read swizzle: chunk holding global chunk q at row (..+c) is q^((c>>1)&3)
  const int swz   = (q ^ ((c >> 1) & 3)) * 8;
  const int aBase = (wm * 128 + c) * 32 + swz;
  const int bBase = 8192 + (wn * 64 + c) * 32 + swz;

  // prologue: stage units 0,1,2 (depth-3); unit0 landed -> pre-read its A frags.
  #pragma unroll
  for (int u = 0; u < 3; ++u) {
    unsigned short* dst = &lds[u * 16384];
    #pragma unroll
    for (int j = 0; j < 4; ++j)
      GLD16(gsrc[j] + u * 64, &dst[ldst[j]]);
  }
  asm volatile("s_waitcnt vmcnt(8)" ::: "memory");
  __builtin_amdgcn_s_barrier();

  bf16x8 fA[2][8];
  #pragma unroll
  for (int mi = 0; mi < 8; ++mi)
    fA[0][mi] = *(const bf16x8*)&lds[aBase + mi * 512];

  f32x4 acc[8][4] = {};

  #pragma unroll
  for (int u = 0; u < 32; ++u) {
    // unit u+1's loads (issued at unit u-2) landed; u+2's may stay in flight.
    asm volatile("s_waitcnt vmcnt(4)" ::: "memory");
    __builtin_amdgcn_s_barrier();

    // stage unit u+3 (wrap: dummy re-stage keeps per-wave vmcnt uniform;
    // clobbered slots provably have no future reads)
    unsigned short* dst = &lds[((u + 3) & 3) * 16384];
    const size_t kb = (size_t)((u + 3) & 31) * 64;
    #pragma unroll
    for (int j = 0; j < 4; ++j)
      GLD16(gsrc[j] + kb, &dst[ldst[j]]);

    // B frags for THIS unit (slot u&3) -- small, compiler interleaves w/ MFMA
    const unsigned short* slC = &lds[(u & 3) * 16384];
    bf16x8 fB[4];
    #pragma unroll
    for (int ni = 0; ni < 4; ++ni)
      fB[ni] = *(const bf16x8*)&slC[bBase + ni * 512];

    // A frags for NEXT unit (slot (u+1)&3) -- execute under the MFMA cluster
    if (u < 31) {
      const unsigned short* slN = &lds[((u + 1) & 3) * 16384];
      #pragma unroll
      for (int mi = 0; mi < 8; ++mi)
        fA[(u + 1) & 1][mi] = *(const bf16x8*)&slN[aBase + mi * 512];
    }

    __builtin_amdgcn_s_setprio(1);
    #pragma unroll
    for (int ni = 0; ni < 4; ++ni)
      #pragma unroll
      for (int mi = 0; mi < 8; ++mi)
        acc[mi][ni] = __builtin_amdgcn_mfma_f32_16x16x32_bf16(fA[u & 1][mi], fB[ni], acc[mi][ni], 0, 0, 0);
    __builtin_amdgcn_s_setprio(0);
  }

  // epilogue: bias + exp + target pick, all in registers
  float bv[4]; int colc[4];
  #pragma unroll
  for (int ni = 0; ni < 4; ++ni) {
    colc[ni] = nBase + wn * 64 + ni * 16 + c;
    bv[ni] = Bv[colc[ni]];
  }

  #pragma unroll
  for (int mi = 0; mi < 8; ++mi) {
    const int rowb = mBase + wm * 128 + mi * 16 + q * 4;
    int tgt4[4];
    #pragma unroll
    for (int r = 0; r < 4; ++r) tgt4[r] = target[rowb + r];
    float se[4] = {0.f, 0.f, 0.f, 0.f};
    float tg[4] = {0.f, 0.f, 0.f, 0.f};
    #pragma unroll
    for (int ni = 0; ni < 4; ++ni)
      #pragma unroll
      for (int r = 0; r < 4; ++r) {
        float logit = acc[mi][ni][r] + bv[ni];
        se[r] += __expf(logit);
        if (tgt4[r] == colc[ni]) tg[r] += logit;
      }
    // quad (16-lane) butterfly, then one atomic pair per row, spread across lanes
    #pragma unroll
    for (int r = 0; r < 4; ++r) {
      float s = se[r];
      float t = tg[r];
      #pragma unroll
      for (int off = 1; off < 16; off <<= 1) {
        s += __shfl_xor(s, off, 64);
        t += __shfl_xor(t, off, 64);
      }
      if (c == ((mi * 4 + r) & 15)) {
        const int row = rowb + r;
        atomicAdd(&ws_se[model * BT + row], s);
        atomicAdd(&ws_tg[model * BT + row], t);
      }
    }
  }
}

// ---------------- fallback (round-1, fp32-convert-in-loop) ----------------
#define SBM 128
#define SBN 128
#define SBK 32
#define SVSLICE 1280
#define SNITER  (SVSLICE / SBN)
#define SKTILES (HDIM / SBK)
#define SLDK    (SBK + 8)

__device__ __forceinline__ void cvt_store8s(unsigned short* dst, float4 a, float4 b) {
  *(u16x8*)dst = cvt8(a, b);
}

__global__ __launch_bounds__(256) void kto_lse_gemm_slow(
    const float* __restrict__ Xp, const float* __restrict__ Wp, const float* __restrict__ Bp,
    const float* __restrict__ Xr, const float* __restrict__ Wr, const float* __restrict__ Br,
    const int* __restrict__ target, float* __restrict__ ws_se, float* __restrict__ ws_tg)
{
  const int model = blockIdx.z;
  const float* __restrict__ X  = model ? Xr : Xp;
  const float* __restrict__ W  = model ? Wr : Wp;
  const float* __restrict__ Bv = model ? Br : Bp;

  __shared__ unsigned short Asm[SBM][SLDK];
  __shared__ unsigned short Bsm[SBN][SLDK];

  const int tid  = threadIdx.x;
  const int wave = tid >> 6;
  const int lane = tid & 63;
  const int q    = lane >> 4;
  const int c    = lane & 15;
  const int mW   = (wave >> 1) * 64;
  const int nW   = (wave & 1) * 64;
  const int mBase = blockIdx.x * SBM;
  const int vBase = blockIdx.y * SVSLICE;

  const int srow = tid >> 1;
  const int scol = (tid & 1) << 4;

  int tgt_idx[4][4];
  #pragma unroll
  for (int mi = 0; mi < 4; ++mi)
    #pragma unroll
    for (int r = 0; r < 4; ++r)
      tgt_idx[mi][r] = target[mBase + mW + mi * 16 + q * 4 + r];

  float se_acc[4][4] = {};
  float tg_acc[4][4] = {};

  for (int it = 0; it < SNITER; ++it) {
    const int nIterBase = vBase + it * SBN;
    f32x4 acc[4][4] = {};

    for (int kt = 0; kt < SKTILES; ++kt) {
      __syncthreads();
      {
        const float4* a4 = (const float4*)(X + (size_t)(mBase + srow) * HDIM + kt * SBK + scol);
        float4 a0 = a4[0], a1 = a4[1], a2 = a4[2], a3 = a4[3];
        const float4* b4 = (const float4*)(W + (size_t)(nIterBase + srow) * HDIM + kt * SBK + scol);
        float4 b0 = b4[0], b1 = b4[1], b2 = b4[2], b3 = b4[3];
        cvt_store8s(&Asm[srow][scol],     a0, a1);
        cvt_store8s(&Asm[srow][scol + 8], a2, a3);
        cvt_store8s(&Bsm[srow][scol],     b0, b1);
        cvt_store8s(&Bsm[srow][scol + 8], b2, b3);
      }
      __syncthreads();

      bf16x8 afr[4], bfr[4];
      #pragma unroll
      for (int mi = 0; mi < 4; ++mi)
        afr[mi] = *(const bf16x8*)&Asm[mW + mi * 16 + c][q * 8];
      #pragma unroll
      for (int ni = 0; ni < 4; ++ni)
        bfr[ni] = *(const bf16x8*)&Bsm[nW + ni * 16 + c][q * 8];
      #pragma unroll
      for (int mi = 0; mi < 4; ++mi)
        #pragma unroll
        for (int ni = 0; ni < 4; ++ni)
          acc[mi][ni] = __builtin_amdgcn_mfma_f32_16x16x32_bf16(afr[mi], bfr[ni], acc[mi][ni], 0, 0, 0);
    }

    #pragma unroll
    for (int ni = 0; ni < 4; ++ni) {
      const int col = nIterBase + nW + ni * 16 + c;
      const float bv = Bv[col];
      #pragma unroll
      for (int mi = 0; mi < 4; ++mi)
        #pragma unroll
        for (int r = 0; r < 4; ++r) {
          float logit = acc[mi][ni][r] + bv;
          se_acc[mi][r] += __expf(logit);
          if (tgt_idx[mi][r] == col) tg_acc[mi][r] += logit;
        }
    }
  }

  #pragma unroll
  for (int mi = 0; mi < 4; ++mi)
    #pragma unroll
    for (int r = 0; r < 4; ++r) {
      float s = se_acc[mi][r];
      float t = tg_acc[mi][r];
      #pragma unroll
      for (int off = 1; off < 16; off <<= 1) {
        s += __shfl_xor(s, off, 64);
        t += __shfl_xor(t, off, 64);
      }
      if (c == 0) {
        const int row = mBase + mW + mi * 16 + q * 4 + r;
        atomicAdd(&ws_se[model * BT + row], s);
        atomicAdd(&ws_tg[model * BT + row], t);
      }
    }
}

__global__ __launch_bounds__(256) void kto_finalize(
    const float* __restrict__ ws_se, const float* __restrict__ ws_tg,
    const int* __restrict__ target, const int* __restrict__ pref,
    const float* __restrict__ kl, float* __restrict__ out)
{
  __shared__ float lr[NSEQ];
  const int tid = threadIdx.x;
  if (tid < NSEQ) lr[tid] = 0.0f;
  __syncthreads();
  for (int t = tid; t < BT; t += 256) {
    float d = 0.0f;
    if (target[t] != IGNORE_IDX) {
      float lp_p = ws_tg[t]      - __logf(ws_se[t]);
      float lp_r = ws_tg[BT + t] - __logf(ws_se[BT + t]);
      d = lp_p - lp_r;
    }
    atomicAdd(&lr[t >> 9], d);
  }
  __syncthreads();
  if (tid == 0) {
    float loss = 0.f, ch = 0.f, rj = 0.f;
    const float klv = kl[0];
    for (int b = 0; b < NSEQ; ++b) {
      float logratio = lr[b];
      bool p = pref[b] != 0;
      float mult = p ? 1.0f : -1.0f;
      float z = BETA * (logratio - klv) * mult;
      float sig = 1.0f / (1.0f + __expf(-z));
      loss += 1.0f - sig;
      float rw = BETA * logratio;
      if (p) ch += rw; else rj += rw;
    }
    out[0] = loss / (float)BT;
    out[1] = ch;
    out[2] = rj;
  }
}

extern "C" void kernel_launch(void* const* d_in, const int* in_sizes, int n_in,
                              void* d_out, int out_size, void* d_ws, size_t ws_size,
                              hipStream_t stream) {
  (void)in_sizes; (void)n_in; (void)out_size;
  const float* X    = (const float*)d_in[0];
  const float* W    = (const float*)d_in[1];
  const int*   tgt  = (const int*)d_in[2];
  const float* bias = (const float*)d_in[3];
  const int*   pref = (const int*)d_in[4];
  const float* Xr   = (const float*)d_in[5];
  const float* Wr   = (const float*)d_in[6];
  const float* br   = (const float*)d_in[7];
  const float* kl   = (const float*)d_in[8];
  float* out = (float*)d_out;

  float* ws_se = (float*)d_ws;
  float* ws_tg = ws_se + 2 * BT;

  kto_zero_ws<<<32, 256, 0, stream>>>(ws_se);  // zero se+tg (8192 floats)

  if (ws_size >= WS_NEED) {
    unsigned short* bf = (unsigned short*)((char*)d_ws + WS_BF_BYTE);
    kto_convert<<<(CVT_TOTAL / 2048), 256, 0, stream>>>(X, Xr, W, Wr, bf);
    dim3 grid(BT / 256, VDIM / 256, 2);  // (8, 125, 2)
    kto_lse_gemm_fast<<<grid, 512, 0, stream>>>(bf, bias, br, tgt, ws_se, ws_tg);
  } else {
    dim3 grid(BT / SBM, VDIM / SVSLICE, 2);  // (16, 25, 2)
    kto_lse_gemm_slow<<<grid, 256, 0, stream>>>(X, W, bias, Xr, Wr, br, tgt, ws_se, ws_tg);
  }

  kto_finalize<<<1, 256, 0, stream>>>(ws_se, ws_tg, tgt, pref, kl, out);
}

// Round 3
// 611.022 us; speedup vs baseline: 1.0354x; 1.0354x over previous
//
#include <hip/hip_runtime.h>

#define BT    2048
#define HDIM  1024
#define VDIM  32000
#define NSEQ  4
#define BETA  0.1f
#define IGNORE_IDX (-100)

typedef __attribute__((ext_vector_type(8))) short bf16x8;
typedef __attribute__((ext_vector_type(8))) unsigned short u16x8;
typedef __attribute__((ext_vector_type(4))) float f32x4;

// ---------------- ws layout ----------------
// floats: [0..4096)  ws_se ([2][BT])   [4096..8192) ws_tg ([2][BT])
// bytes 32768+: bf16 arrays: Xbf, Xrbf, Wbf, Wrbf (element offsets below)
#define WS_BF_BYTE  32768
#define XBF_OFF     0
#define XRBF_OFF    (BT * HDIM)                    // 2097152
#define WBF_OFF     (2 * BT * HDIM)                // 4194304
#define WRBF_OFF    (2 * BT * HDIM + VDIM * HDIM)  // 36962304
#define CVT_TOTAL   (2 * BT * HDIM + 2 * VDIM * HDIM)  // 69730304
#define WS_NEED     ((size_t)WS_BF_BYTE + (size_t)CVT_TOTAL * 2)

__device__ __forceinline__ unsigned short f2bf_rne(float f) {
  unsigned int u = __builtin_bit_cast(unsigned int, f);
  u += 0x7fffu + ((u >> 16) & 1u);
  return (unsigned short)(u >> 16);
}

__device__ __forceinline__ u16x8 cvt8(float4 a, float4 b) {
  u16x8 v;
  v[0] = f2bf_rne(a.x); v[1] = f2bf_rne(a.y); v[2] = f2bf_rne(a.z); v[3] = f2bf_rne(a.w);
  v[4] = f2bf_rne(b.x); v[5] = f2bf_rne(b.y); v[6] = f2bf_rne(b.z); v[7] = f2bf_rne(b.w);
  return v;
}

__global__ __launch_bounds__(256) void kto_zero_ws(float* p) {
  p[blockIdx.x * 256 + threadIdx.x] = 0.0f;
}

// fp32 -> bf16 one-shot conversion of X, Xr, W, Wr into ws. HBM-bound.
__global__ __launch_bounds__(256) void kto_convert(
    const float* __restrict__ X, const float* __restrict__ Xr,
    const float* __restrict__ W, const float* __restrict__ Wr,
    unsigned short* __restrict__ bf)
{
  size_t gid8 = ((size_t)blockIdx.x * 256 + threadIdx.x) * 8;
  if (gid8 >= (size_t)CVT_TOTAL) return;
  const float* src; size_t off;
  if (gid8 < (size_t)XRBF_OFF)      { src = X;  off = gid8; }
  else if (gid8 < (size_t)WBF_OFF)  { src = Xr; off = gid8 - XRBF_OFF; }
  else if (gid8 < (size_t)WRBF_OFF) { src = W;  off = gid8 - WBF_OFF; }
  else                              { src = Wr; off = gid8 - WRBF_OFF; }
  const float4* p = (const float4*)(src + off);
  float4 a = p[0], b = p[1];
  *(u16x8*)(bf + gid8) = cvt8(a, b);
}

#define GLD16(g, l) __builtin_amdgcn_global_load_lds( \
    (const __attribute__((address_space(1))) unsigned int*)(g), \
    (__attribute__((address_space(3))) unsigned int*)(l), 16, 0, 0)

// 256x256-tile GEMM + logsumexp partials, m201-template schedule.
// grid = (BT/256, VDIM/256, 2 models) = (8, 125, 2), block = 512 (8 waves, 2Mx4N).
// LDS: 4 rotating 32KB slots (K-32 slices). Unit u: read slot u&3, stage unit
// u+3 into slot (u+3)&3 (distinct from u&3 and (u+1)&3 -> no overlap).
// Per unit: 2 phases. Phase = { ds_read frags (BEFORE barrier -> latency hides
// under rendezvous) | 2 GLD | barrier | lgkmcnt(0) | setprio(1) 16 MFMA
// setprio(0) | barrier }.  One counted vmcnt(8) per unit at phase B: the 8
// newest GLDs (units u+2,u+3) stay in flight; unit u+1 (issued at u-2, ~3
// units of slack) is provably landed before the next unit reads it.
// Race audit: phase-A reads of slot u are ordered after unit u-1's
// vmcnt(8)+barrier (slot u landed). GLDs target slot (u-1)&3, whose last
// reads were lgkm-drained before unit u-1's final barrier. Wrap GLDs
// (u>=29) re-stage early units into slots with no future reads.
__global__ __launch_bounds__(512, 2) void kto_lse_gemm_fast(
    const unsigned short* __restrict__ bf,
    const float* __restrict__ Bp, const float* __restrict__ Br,
    const int* __restrict__ target,
    float* __restrict__ ws_se, float* __restrict__ ws_tg)
{
  const int model = blockIdx.z;
  const unsigned short* __restrict__ Xb = bf + (model ? XRBF_OFF : XBF_OFF);
  const unsigned short* __restrict__ Wb = bf + (model ? WRBF_OFF : WBF_OFF);
  const float* __restrict__ Bv = model ? Br : Bp;

  // T1: bijective XCD swizzle. nwg=1000 per model, 8 XCDs, 125 blocks/XCD.
  const int lin  = blockIdx.x + (blockIdx.y << 3);
  const int wgid = (lin & 7) * 125 + (lin >> 3);
  const int mBase = (wgid & 7) * 256;
  const int nBase = (wgid >> 3) * 256;

  __shared__ unsigned short lds[4 * 16384];  // 128 KiB

  const int tid  = threadIdx.x;
  const int wave = tid >> 6;
  const int lane = tid & 63;
  const int q    = lane >> 4;
  const int c    = lane & 15;
  const int wm   = wave >> 2;   // 0..1  (M half)
  const int wn   = wave & 3;    // 0..3  (N quarter)

  // staging: unit = 32 segments of 1KB (16 rows x 64B); wave w owns segs 4w..4w+3.
  // LDS dest = wave-uniform base + lane*16 (linear). Source global chunk is
  // XOR-pre-swizzled so the read-side swizzle below finds its data (rule 21).
  const int lrow = lane >> 2;                       // row within 16-row segment
  const int lchk = (lane & 3) ^ ((lane >> 3) & 3);  // pre-swizzled 16B chunk

  const char* gsrc[4];
  int ldst[4];
  #pragma unroll
  for (int j = 0; j < 4; ++j) {
    const int seg = wave * 4 + j;
    if (seg < 16) {                                  // A: 16 segs = 256 rows
      const int row = mBase + seg * 16 + lrow;
      gsrc[j] = (const char*)Xb + (size_t)row * (HDIM * 2) + lchk * 16;
      ldst[j] = seg * 512;
    } else {                                         // B: 16 segs = 256 rows
      const int row = nBase + (seg - 16) * 16 + lrow;
      gsrc[j] = (const char*)Wb + (size_t)row * (HDIM * 2) + lchk * 16;
      ldst[j] = 8192 + (seg - 16) * 512;
    }
  }

  // frag-read swizzle: chunk holding global chunk q at row (..+c) is q^((c>>1)&3)
  const int swz   = (q ^ ((c >> 1) & 3)) * 8;
  const int aBase = (wm * 128 + c) * 32 + swz;
  const int bBase = 8192 + (wn * 64 + c) * 32 + swz;

  // prologue: stage units 0,1,2 (depth-3); vmcnt(8) -> unit 0 landed.
  #pragma unroll
  for (int u = 0; u < 3; ++u) {
    unsigned short* dst = &lds[u * 16384];
    #pragma unroll
    for (int j = 0; j < 4; ++j)
      GLD16(gsrc[j] + u * 64, &dst[ldst[j]]);
  }
  asm volatile("s_waitcnt vmcnt(8)" ::: "memory");
  __builtin_amdgcn_s_barrier();

  f32x4 acc[8][4] = {};

  for (int u = 0; u < 32; ++u) {
    const unsigned short* sl = &lds[(u & 3) * 16384];
    unsigned short* dst = &lds[((u + 3) & 3) * 16384];
    const size_t kb = (size_t)((u + 3) & 31) * 64;  // wrap: dummy re-stages
                                                    // keep vmcnt counts uniform

    // ---- phase A: reads + 2 GLD issued BEFORE barrier ----
    bf16x8 fB[4], fA[4];
    #pragma unroll
    for (int ni = 0; ni < 4; ++ni)
      fB[ni] = *(const bf16x8*)&sl[bBase + ni * 512];
    #pragma unroll
    for (int mi = 0; mi < 4; ++mi)
      fA[mi] = *(const bf16x8*)&sl[aBase + mi * 512];
    GLD16(gsrc[0] + kb, &dst[ldst[0]]);
    GLD16(gsrc[1] + kb, &dst[ldst[1]]);
    __builtin_amdgcn_sched_barrier(0);
    __builtin_amdgcn_s_barrier();
    asm volatile("s_waitcnt lgkmcnt(0)" ::: "memory");
    __builtin_amdgcn_sched_barrier(0);
    __builtin_amdgcn_s_setprio(1);
    #pragma unroll
    for (int mi = 0; mi < 4; ++mi)
      #pragma unroll
      for (int ni = 0; ni < 4; ++ni)
        acc[mi][ni] = __builtin_amdgcn_mfma_f32_16x16x32_bf16(fA[mi], fB[ni], acc[mi][ni], 0, 0, 0);
    __builtin_amdgcn_s_setprio(0);
    __builtin_amdgcn_sched_barrier(0);
    __builtin_amdgcn_s_barrier();

    // ---- phase B: reads + 2 GLD before barrier, counted vmcnt once/unit ----
    bf16x8 fA2[4];
    #pragma unroll
    for (int mi = 0; mi < 4; ++mi)
      fA2[mi] = *(const bf16x8*)&sl[aBase + 2048 + mi * 512];
    GLD16(gsrc[2] + kb, &dst[ldst[2]]);
    GLD16(gsrc[3] + kb, &dst[ldst[3]]);
    // newest 8 (units u+2,u+3) may stay in flight; unit u+1 is landed.
    asm volatile("s_waitcnt vmcnt(8)" ::: "memory");
    __builtin_amdgcn_sched_barrier(0);
    __builtin_amdgcn_s_barrier();
    asm volatile("s_waitcnt lgkmcnt(0)" ::: "memory");
    __builtin_amdgcn_sched_barrier(0);
    __builtin_amdgcn_s_setprio(1);
    #pragma unroll
    for (int mi = 0; mi < 4; ++mi)
      #pragma unroll
      for (int ni = 0; ni < 4; ++ni)
        acc[mi + 4][ni] = __builtin_amdgcn_mfma_f32_16x16x32_bf16(fA2[mi], fB[ni], acc[mi + 4][ni], 0, 0, 0);
    __builtin_amdgcn_s_setprio(0);
    __builtin_amdgcn_sched_barrier(0);
    __builtin_amdgcn_s_barrier();
  }

  // epilogue: bias + exp + target pick, all in registers
  float bv[4]; int colc[4];
  #pragma unroll
  for (int ni = 0; ni < 4; ++ni) {
    colc[ni] = nBase + wn * 64 + ni * 16 + c;
    bv[ni] = Bv[colc[ni]];
  }

  #pragma unroll
  for (int mi = 0; mi < 8; ++mi) {
    const int rowb = mBase + wm * 128 + mi * 16 + q * 4;
    int tgt4[4];
    #pragma unroll
    for (int r = 0; r < 4; ++r) tgt4[r] = target[rowb + r];
    float se[4] = {0.f, 0.f, 0.f, 0.f};
    float tg[4] = {0.f, 0.f, 0.f, 0.f};
    #pragma unroll
    for (int ni = 0; ni < 4; ++ni)
      #pragma unroll
      for (int r = 0; r < 4; ++r) {
        float logit = acc[mi][ni][r] + bv[ni];
        se[r] += __expf(logit);
        if (tgt4[r] == colc[ni]) tg[r] += logit;
      }
    // quad (16-lane) butterfly, then one atomic pair per row, spread across lanes
    #pragma unroll
    for (int r = 0; r < 4; ++r) {
      float s = se[r];
      float t = tg[r];
      #pragma unroll
      for (int off = 1; off < 16; off <<= 1) {
        s += __shfl_xor(s, off, 64);
        t += __shfl_xor(t, off, 64);
      }
      if (c == ((mi * 4 + r) & 15)) {
        const int row = rowb + r;
        atomicAdd(&ws_se[model * BT + row], s);
        atomicAdd(&ws_tg[model * BT + row], t);
      }
    }
  }
}

// ---------------- fallback (round-1, fp32-convert-in-loop) ----------------
#define SBM 128
#define SBN 128
#define SBK 32
#define SVSLICE 1280
#define SNITER  (SVSLICE / SBN)
#define SKTILES (HDIM / SBK)
#define SLDK    (SBK + 8)

__device__ __forceinline__ void cvt_store8s(unsigned short* dst, float4 a, float4 b) {
  *(u16x8*)dst = cvt8(a, b);
}

__global__ __launch_bounds__(256) void kto_lse_gemm_slow(
    const float* __restrict__ Xp, const float* __restrict__ Wp, const float* __restrict__ Bp,
    const float* __restrict__ Xr, const float* __restrict__ Wr, const float* __restrict__ Br,
    const int* __restrict__ target, float* __restrict__ ws_se, float* __restrict__ ws_tg)
{
  const int model = blockIdx.z;
  const float* __restrict__ X  = model ? Xr : Xp;
  const float* __restrict__ W  = model ? Wr : Wp;
  const float* __restrict__ Bv = model ? Br : Bp;

  __shared__ unsigned short Asm[SBM][SLDK];
  __shared__ unsigned short Bsm[SBN][SLDK];

  const int tid  = threadIdx.x;
  const int wave = tid >> 6;
  const int lane = tid & 63;
  const int q    = lane >> 4;
  const int c    = lane & 15;
  const int mW   = (wave >> 1) * 64;
  const int nW   = (wave & 1) * 64;
  const int mBase = blockIdx.x * SBM;
  const int vBase = blockIdx.y * SVSLICE;

  const int srow = tid >> 1;
  const int scol = (tid & 1) << 4;

  int tgt_idx[4][4];
  #pragma unroll
  for (int mi = 0; mi < 4; ++mi)
    #pragma unroll
    for (int r = 0; r < 4; ++r)
      tgt_idx[mi][r] = target[mBase + mW + mi * 16 + q * 4 + r];

  float se_acc[4][4] = {};
  float tg_acc[4][4] = {};

  for (int it = 0; it < SNITER; ++it) {
    const int nIterBase = vBase + it * SBN;
    f32x4 acc[4][4] = {};

    for (int kt = 0; kt < SKTILES; ++kt) {
      __syncthreads();
      {
        const float4* a4 = (const float4*)(X + (size_t)(mBase + srow) * HDIM + kt * SBK + scol);
        float4 a0 = a4[0], a1 = a4[1], a2 = a4[2], a3 = a4[3];
        const float4* b4 = (const float4*)(W + (size_t)(nIterBase + srow) * HDIM + kt * SBK + scol);
        float4 b0 = b4[0], b1 = b4[1], b2 = b4[2], b3 = b4[3];
        cvt_store8s(&Asm[srow][scol],     a0, a1);
        cvt_store8s(&Asm[srow][scol + 8], a2, a3);
        cvt_store8s(&Bsm[srow][scol],     b0, b1);
        cvt_store8s(&Bsm[srow][scol + 8], b2, b3);
      }
      __syncthreads();

      bf16x8 afr[4], bfr[4];
      #pragma unroll
      for (int mi = 0; mi < 4; ++mi)
        afr[mi] = *(const bf16x8*)&Asm[mW + mi * 16 + c][q * 8];
      #pragma unroll
      for (int ni = 0; ni < 4; ++ni)
        bfr[ni] = *(const bf16x8*)&Bsm[nW + ni * 16 + c][q * 8];
      #pragma unroll
      for (int mi = 0; mi < 4; ++mi)
        #pragma unroll
        for (int ni = 0; ni < 4; ++ni)
          acc[mi][ni] = __builtin_amdgcn_mfma_f32_16x16x32_bf16(afr[mi], bfr[ni], acc[mi][ni], 0, 0, 0);
    }

    #pragma unroll
    for (int ni = 0; ni < 4; ++ni) {
      const int col = nIterBase + nW + ni * 16 + c;
      const float bv = Bv[col];
      #pragma unroll
      for (int mi = 0; mi < 4; ++mi)
        #pragma unroll
        for (int r = 0; r < 4; ++r) {
          float logit = acc[mi][ni][r] + bv;
          se_acc[mi][r] += __expf(logit);
          if (tgt_idx[mi][r] == col) tg_acc[mi][r] += logit;
        }
    }
  }

  #pragma unroll
  for (int mi = 0; mi < 4; ++mi)
    #pragma unroll
    for (int r = 0; r < 4; ++r) {
      float s = se_acc[mi][r];
      float t = tg_acc[mi][r];
      #pragma unroll
      for (int off = 1; off < 16; off <<= 1) {
        s += __shfl_xor(s, off, 64);
        t += __shfl_xor(t, off, 64);
      }
      if (c == 0) {
        const int row = mBase + mW + mi * 16 + q * 4 + r;
        atomicAdd(&ws_se[model * BT + row], s);
        atomicAdd(&ws_tg[model * BT + row], t);
      }
    }
}

__global__ __launch_bounds__(256) void kto_finalize(
    const float* __restrict__ ws_se, const float* __restrict__ ws_tg,
    const int* __restrict__ target, const int* __restrict__ pref,
    const float* __restrict__ kl, float* __restrict__ out)
{
  __shared__ float lr[NSEQ];
  const int tid = threadIdx.x;
  if (tid < NSEQ) lr[tid] = 0.0f;
  __syncthreads();
  for (int t = tid; t < BT; t += 256) {
    float d = 0.0f;
    if (target[t] != IGNORE_IDX) {
      float lp_p = ws_tg[t]      - __logf(ws_se[t]);
      float lp_r = ws_tg[BT + t] - __logf(ws_se[BT + t]);
      d = lp_p - lp_r;
    }
    atomicAdd(&lr[t >> 9], d);
  }
  __syncthreads();
  if (tid == 0) {
    float loss = 0.f, ch = 0.f, rj = 0.f;
    const float klv = kl[0];
    for (int b = 0; b < NSEQ; ++b) {
      float logratio = lr[b];
      bool p = pref[b] != 0;
      float mult = p ? 1.0f : -1.0f;
      float z = BETA * (logratio - klv) * mult;
      float sig = 1.0f / (1.0f + __expf(-z));
      loss += 1.0f - sig;
      float rw = BETA * logratio;
      if (p) ch += rw; else rj += rw;
    }
    out[0] = loss / (float)BT;
    out[1] = ch;
    out[2] = rj;
  }
}

extern "C" void kernel_launch(void* const* d_in, const int* in_sizes, int n_in,
                              void* d_out, int out_size, void* d_ws, size_t ws_size,
                              hipStream_t stream) {
  (void)in_sizes; (void)n_in; (void)out_size;
  const float* X    = (const float*)d_in[0];
  const float* W    = (const float*)d_in[1];
  const int*   tgt  = (const int*)d_in[2];
  const float* bias = (const float*)d_in[3];
  const int*   pref = (const int*)d_in[4];
  const float* Xr   = (const float*)d_in[5];
  const float* Wr   = (const float*)d_in[6];
  const float* br   = (const float*)d_in[7];
  const float* kl   = (const float*)d_in[8];
  float* out = (float*)d_out;

  float* ws_se = (float*)d_ws;
  float* ws_tg = ws_se + 2 * BT;

  kto_zero_ws<<<32, 256, 0, stream>>>(ws_se);  // zero se+tg (8192 floats)

  if (ws_size >= WS_NEED) {
    unsigned short* bf = (unsigned short*)((char*)d_ws + WS_BF_BYTE);
    kto_convert<<<(CVT_TOTAL / 2048), 256, 0, stream>>>(X, Xr, W, Wr, bf);
    dim3 grid(BT / 256, VDIM / 256, 2);  // (8, 125, 2)
    kto_lse_gemm_fast<<<grid, 512, 0, stream>>>(bf, bias, br, tgt, ws_se, ws_tg);
  } else {
    dim3 grid(BT / SBM, VDIM / SVSLICE, 2);  // (16, 25, 2)
    kto_lse_gemm_slow<<<grid, 256, 0, stream>>>(X, W, bias, Xr, Wr, br, tgt, ws_se, ws_tg);
  }

  kto_finalize<<<1, 256, 0, stream>>>(ws_se, ws_tg, tgt, pref, kl, out);
}